// Round 1
// baseline (135.106 us; speedup 1.0000x reference)
//
#include <hip/hip_runtime.h>

// VQ lookup: argmin_k ||z - c_k||^2 then gather codebook rows.
// N = 32*32*32 = 32768 queries, D = 128, K = 1024. All fp32.
// score(q,k) = csq[k] - 2*dot(z_q, c_k)   (z_sq dropped: constant per query)

#define NQ 32768
#define DIM 128
#define KCB 1024
#define QT 64   // queries per block
#define KT 64   // k per k-tile
#define TQ 4    // queries per thread
#define TK 4    // k per thread

__global__ __launch_bounds__(256) void vq_csq_kernel(const float* __restrict__ cb,
                                                     float* __restrict__ csq) {
    int k = blockIdx.x * blockDim.x + threadIdx.x;
    if (k < KCB) {
        const float4* row = (const float4*)(cb + (size_t)k * DIM);
        float s = 0.f;
        #pragma unroll
        for (int i = 0; i < DIM / 4; ++i) {
            float4 v = row[i];
            s += v.x * v.x + v.y * v.y + v.z * v.z + v.w * v.w;
        }
        csq[k] = s;
    }
}

__global__ __launch_bounds__(256, 2) void vq_main_kernel(const float* __restrict__ z,
                                                         const float* __restrict__ cb,
                                                         const float* __restrict__ csq,
                                                         float* __restrict__ out) {
    __shared__ float zT[DIM][QT];      // 32 KB, transposed: zT[d][q]
    __shared__ float cT[DIM][KT];      // 32 KB, transposed: cT[d][k]
    __shared__ float red_v[QT][16];    // 4 KB
    __shared__ int   red_i[QT][16];    // 4 KB
    __shared__ int   kmin_s[QT];

    const int t  = threadIdx.x;
    const int tx = t & 15;   // k direction
    const int ty = t >> 4;   // query direction
    const int qbase = blockIdx.x * QT;

    // ---- stage zT once: 64 rows x 32 float4, 4 threads per row ----
    {
        int r  = t >> 2;        // 0..63
        int c0 = t & 3;         // 0..3
        const float4* src = (const float4*)(z + (size_t)(qbase + r) * DIM);
        #pragma unroll
        for (int i = 0; i < 8; ++i) {
            float4 v = src[c0 + 4 * i];
            int d = (c0 + 4 * i) * 4;
            zT[d + 0][r] = v.x;
            zT[d + 1][r] = v.y;
            zT[d + 2][r] = v.z;
            zT[d + 3][r] = v.w;
        }
    }

    float minv[TQ];
    int   mini[TQ];
    #pragma unroll
    for (int i = 0; i < TQ; ++i) { minv[i] = 3.4e38f; mini[i] = 0; }

    for (int kt = 0; kt < KCB / KT; ++kt) {
        const int kbase = kt * KT;
        __syncthreads();   // previous tile's readers done (also covers zT stage on kt=0)

        // ---- stage cT: 64 rows x 32 float4 ----
        {
            int r  = t >> 2;
            int c0 = t & 3;
            const float4* src = (const float4*)(cb + (size_t)(kbase + r) * DIM);
            #pragma unroll
            for (int i = 0; i < 8; ++i) {
                float4 v = src[c0 + 4 * i];
                int d = (c0 + 4 * i) * 4;
                cT[d + 0][r] = v.x;
                cT[d + 1][r] = v.y;
                cT[d + 2][r] = v.z;
                cT[d + 3][r] = v.w;
            }
        }

        // csq for my 4 k's (issued early, used after d-loop; latency hidden)
        float cs[TK];
        #pragma unroll
        for (int j = 0; j < TK; ++j) cs[j] = csq[kbase + tx * TK + j];

        __syncthreads();

        float acc[TQ][TK] = {};
        #pragma unroll 4
        for (int d = 0; d < DIM; ++d) {
            float4 zv = *(const float4*)&zT[d][ty * TQ];
            float4 cv = *(const float4*)&cT[d][tx * TK];
            float zr[4] = {zv.x, zv.y, zv.z, zv.w};
            float cr[4] = {cv.x, cv.y, cv.z, cv.w};
            #pragma unroll
            for (int i = 0; i < TQ; ++i)
                #pragma unroll
                for (int j = 0; j < TK; ++j)
                    acc[i][j] = fmaf(zr[i], cr[j], acc[i][j]);
        }

        // fold into running argmin (strict < keeps earliest k; k ascending)
        #pragma unroll
        for (int i = 0; i < TQ; ++i) {
            #pragma unroll
            for (int j = 0; j < TK; ++j) {
                float score = fmaf(-2.0f, acc[i][j], cs[j]);
                int kk = kbase + tx * TK + j;
                if (score < minv[i]) { minv[i] = score; mini[i] = kk; }
            }
        }
    }

    // ---- cross-thread argmin reduction (16 tx slices per query) ----
    __syncthreads();
    #pragma unroll
    for (int i = 0; i < TQ; ++i) {
        red_v[ty * TQ + i][tx] = minv[i];
        red_i[ty * TQ + i][tx] = mini[i];
    }
    __syncthreads();
    if (t < QT) {
        float bv = red_v[t][0];
        int   bi = red_i[t][0];
        #pragma unroll
        for (int x = 1; x < 16; ++x) {
            float v  = red_v[t][x];
            int   ii = red_i[t][x];
            if (v < bv || (v == bv && ii < bi)) { bv = v; bi = ii; }
        }
        kmin_s[t] = bi;
    }
    __syncthreads();

    // ---- gather winning codebook rows to output ----
    {
        int r  = t >> 2;
        int c0 = t & 3;
        const float4* src = (const float4*)(cb + (size_t)kmin_s[r] * DIM);
        float4*       dst = (float4*)(out + (size_t)(qbase + r) * DIM);
        #pragma unroll
        for (int i = 0; i < 8; ++i) dst[c0 + 4 * i] = src[c0 + 4 * i];
    }
}

extern "C" void kernel_launch(void* const* d_in, const int* in_sizes, int n_in,
                              void* d_out, int out_size, void* d_ws, size_t ws_size,
                              hipStream_t stream) {
    const float* z  = (const float*)d_in[0];   // inputs [32,32,32,128]
    const float* cb = (const float*)d_in[1];   // codebook [1024,128]
    float* csq = (float*)d_ws;                 // 1024 floats scratch
    float* out = (float*)d_out;

    vq_csq_kernel<<<KCB / 256, 256, 0, stream>>>(cb, csq);
    vq_main_kernel<<<NQ / QT, 256, 0, stream>>>(z, cb, csq, out);
}

// Round 2
// 129.176 us; speedup vs baseline: 1.0459x; 1.0459x over previous
//
#include <hip/hip_runtime.h>

// VQ lookup: argmin_k ||z - c_k||^2 then gather codebook rows.
// N = 32768 queries, D = 128, K = 1024, fp32.
// score(q,k) = csq[k] - 2*dot(z_q, c_k)  (z_sq constant per query, dropped)
//
// Round-2 structure: block = 512 thr (16 tx x 32 ty), tile 128q x 128k,
// TQ=4 TK=8 -> 3 b128 LDS reads per 32 FMA (VALU-led, not LDS co-limited).
// c stored as two half-arrays cA/cB so each b128 read is the free 2-way
// [d][tx*4] bank pattern. Grid = 256 blocks = exactly 1 per CU.

#define NQ 32768
#define DIM 128
#define KCB 1024
#define QT 128
#define KT 128
#define TQ 4
#define TK 8
#define BLK 512

__global__ __launch_bounds__(256) void vq_csq_kernel(const float* __restrict__ cb,
                                                     float* __restrict__ csq) {
    int k = blockIdx.x * blockDim.x + threadIdx.x;
    if (k < KCB) {
        const float4* row = (const float4*)(cb + (size_t)k * DIM);
        float s = 0.f;
        #pragma unroll
        for (int i = 0; i < DIM / 4; ++i) {
            float4 v = row[i];
            s += v.x * v.x + v.y * v.y + v.z * v.z + v.w * v.w;
        }
        csq[k] = s;
    }
}

__global__ __launch_bounds__(BLK, 1) void vq_main_kernel(const float* __restrict__ z,
                                                         const float* __restrict__ cb,
                                                         const float* __restrict__ csq,
                                                         float* __restrict__ out) {
    __shared__ float zT[DIM][QT];       // 64 KB, zT[d][q]
    __shared__ float cA[DIM][KT / 2];   // 32 KB, cA[d][tx*4+j] = c[k0+tx*8+j][d]
    __shared__ float cB[DIM][KT / 2];   // 32 KB, cB[d][tx*4+j] = c[k0+tx*8+4+j][d]
    __shared__ int   kmin_s[QT];        // 0.5 KB

    const int t  = threadIdx.x;
    const int tx = t & 15;    // k direction (16)
    const int ty = t >> 4;    // query direction (32)
    const int qbase = blockIdx.x * QT;

    // staging role: 4 threads per row, row r, col-phase c0
    const int r  = t >> 2;    // 0..127
    const int c0 = t & 3;     // 0..3
    // c destination: logical k-offset r -> (array e, col m)
    const int e = (r >> 2) & 1;
    const int m = ((r >> 3) << 2) | (r & 3);
    float* const cdst = (e ? &cB[0][0] : &cA[0][0]) + m;

    // ---- prologue: load z slab + c tile 0, write transposed ----
    float4 pf[8];
    {
        const float4* zsrc = (const float4*)(z + (size_t)(qbase + r) * DIM);
        const float4* csrc = (const float4*)(cb + (size_t)r * DIM);
        float4 zf[8];
        #pragma unroll
        for (int i = 0; i < 8; ++i) zf[i] = zsrc[c0 + 4 * i];
        #pragma unroll
        for (int i = 0; i < 8; ++i) pf[i] = csrc[c0 + 4 * i];
        #pragma unroll
        for (int i = 0; i < 8; ++i) {
            int d = (c0 + 4 * i) * 4;
            zT[d + 0][r] = zf[i].x;
            zT[d + 1][r] = zf[i].y;
            zT[d + 2][r] = zf[i].z;
            zT[d + 3][r] = zf[i].w;
        }
        #pragma unroll
        for (int i = 0; i < 8; ++i) {
            int d = (c0 + 4 * i) * 4;
            cdst[(d + 0) * (KT / 2)] = pf[i].x;
            cdst[(d + 1) * (KT / 2)] = pf[i].y;
            cdst[(d + 2) * (KT / 2)] = pf[i].z;
            cdst[(d + 3) * (KT / 2)] = pf[i].w;
        }
    }
    __syncthreads();

    float minv[TQ];
    int   mini[TQ];
    #pragma unroll
    for (int i = 0; i < TQ; ++i) { minv[i] = 3.4e38f; mini[i] = 0; }

    for (int kt = 0; kt < KCB / KT; ++kt) {
        const int kbase = kt * KT;

        // T14: issue next c-tile's global loads now; LDS-write after barrier
        if (kt < KCB / KT - 1) {
            const float4* nsrc = (const float4*)(cb + (size_t)(kbase + KT + r) * DIM);
            #pragma unroll
            for (int i = 0; i < 8; ++i) pf[i] = nsrc[c0 + 4 * i];
        }
        const float4 cs0 = *(const float4*)(csq + kbase + tx * 8);
        const float4 cs1 = *(const float4*)(csq + kbase + tx * 8 + 4);

        float acc[TQ][TK] = {};
        #pragma unroll 4
        for (int d = 0; d < DIM; ++d) {
            float4 zv = *(const float4*)&zT[d][ty * TQ];
            float4 va = *(const float4*)&cA[d][tx * 4];
            float4 vb = *(const float4*)&cB[d][tx * 4];
            float zr[TQ] = {zv.x, zv.y, zv.z, zv.w};
            float cr[TK] = {va.x, va.y, va.z, va.w, vb.x, vb.y, vb.z, vb.w};
            #pragma unroll
            for (int i = 0; i < TQ; ++i)
                #pragma unroll
                for (int j = 0; j < TK; ++j)
                    acc[i][j] = fmaf(zr[i], cr[j], acc[i][j]);
        }

        // fold into running argmin (ascending k, strict < keeps earliest)
        const float cs[TK] = {cs0.x, cs0.y, cs0.z, cs0.w, cs1.x, cs1.y, cs1.z, cs1.w};
        #pragma unroll
        for (int i = 0; i < TQ; ++i) {
            #pragma unroll
            for (int j = 0; j < TK; ++j) {
                float score = fmaf(-2.0f, acc[i][j], cs[j]);
                int kk = kbase + tx * TK + j;
                if (score < minv[i]) { minv[i] = score; mini[i] = kk; }
            }
        }

        __syncthreads();   // all waves done reading cA/cB
        if (kt < KCB / KT - 1) {
            #pragma unroll
            for (int i = 0; i < 8; ++i) {
                int d = (c0 + 4 * i) * 4;
                cdst[(d + 0) * (KT / 2)] = pf[i].x;
                cdst[(d + 1) * (KT / 2)] = pf[i].y;
                cdst[(d + 2) * (KT / 2)] = pf[i].z;
                cdst[(d + 3) * (KT / 2)] = pf[i].w;
            }
            __syncthreads();
        }
    }

    // ---- cross-tx argmin: 16-lane lexicographic shuffle reduce ----
    #pragma unroll
    for (int i = 0; i < TQ; ++i) {
        float bv = minv[i];
        int   bi = mini[i];
        #pragma unroll
        for (int off = 1; off < 16; off <<= 1) {
            float vo = __shfl_xor(bv, off);
            int   io = __shfl_xor(bi, off);
            if (vo < bv || (vo == bv && io < bi)) { bv = vo; bi = io; }
        }
        if (tx == 0) kmin_s[ty * TQ + i] = bi;
    }
    __syncthreads();

    // ---- gather winning codebook rows ----
    {
        const int kk = kmin_s[r];
        const float4* src = (const float4*)(cb + (size_t)kk * DIM);
        float4*       dst = (float4*)(out + (size_t)(qbase + r) * DIM);
        #pragma unroll
        for (int i = 0; i < 8; ++i) dst[c0 + 4 * i] = src[c0 + 4 * i];
    }
}

extern "C" void kernel_launch(void* const* d_in, const int* in_sizes, int n_in,
                              void* d_out, int out_size, void* d_ws, size_t ws_size,
                              hipStream_t stream) {
    const float* z  = (const float*)d_in[0];   // inputs [32,32,32,128]
    const float* cb = (const float*)d_in[1];   // codebook [1024,128]
    float* csq = (float*)d_ws;                 // 1024 floats scratch
    float* out = (float*)d_out;

    vq_csq_kernel<<<KCB / 256, 256, 0, stream>>>(cb, csq);
    vq_main_kernel<<<NQ / QT, BLK, 0, stream>>>(z, cb, csq, out);
}